// Round 14
// baseline (1153.641 us; speedup 1.0000x reference)
//
#include <hip/hip_runtime.h>
#include <hip/hip_bf16.h>

#define DM 1024
#define SLEN 2048
#define MROWS 4096   // B*S
#define QKVLD 3072
#define SC 0.18033688f   // 0.125 * log2(e), folded into Wq/bq

typedef short  short8 __attribute__((ext_vector_type(8)));
typedef float  f32x4  __attribute__((ext_vector_type(4)));
typedef unsigned short u16x4 __attribute__((ext_vector_type(4)));

__device__ __forceinline__ unsigned short f2bf(float f) {
  __hip_bfloat16 h = __float2bfloat16(f);
  return __builtin_bit_cast(unsigned short, h);
}

__device__ __forceinline__ void gload16(const void* g, void* l) {
  __builtin_amdgcn_global_load_lds(
      (const __attribute__((address_space(1))) unsigned int*)g,
      (__attribute__((address_space(3))) unsigned int*)l, 16, 0, 0);
}

// ---------------- Wq/Wk/Wv/Wo transpose+cvt in ONE launch (grid.z picks) ----------------
__global__ __launch_bounds__(256) void tr_qkvo(
    const float* __restrict__ Wq, const float* __restrict__ Wk,
    const float* __restrict__ Wv, const float* __restrict__ Wo,
    unsigned short* __restrict__ wt)
{
  __shared__ float t[32][33];
  const int z = blockIdx.z;
  const float* W = (z == 0) ? Wq : (z == 1) ? Wk : (z == 2) ? Wv : Wo;
  const float scale = (z == 0) ? SC : 1.f;
  unsigned short* dst = wt + (size_t)z * 1024 * 1024;
  const int k0 = blockIdx.y * 32, n0 = blockIdx.x * 32;
  const int tid = threadIdx.x;
  const int row = tid >> 3, c4 = (tid & 7) * 4;
  const float4 v = *(const float4*)&W[(size_t)(k0 + row) * DM + n0 + c4];
  t[row][c4 + 0] = v.x; t[row][c4 + 1] = v.y;
  t[row][c4 + 2] = v.z; t[row][c4 + 3] = v.w;
  __syncthreads();
  u16x4 ov;
  #pragma unroll
  for (int j = 0; j < 4; ++j) ov[j] = f2bf(t[c4 + j][row] * scale);
  *(u16x4*)&dst[(size_t)(n0 + row) * DM + k0 + c4] = ov;
}

// ---------------- W1 + W2 transpose+cvt in ONE launch ----------------
__global__ __launch_bounds__(256) void tr_w12(
    const float* __restrict__ W1, const float* __restrict__ W2,
    unsigned short* __restrict__ w1t, unsigned short* __restrict__ w2t)
{
  __shared__ float t[32][33];
  int id = blockIdx.x;
  const float* W; unsigned short* dst; int K, N, bx, by;
  if (id < 4096) { W = W1; dst = w1t; K = 1024; N = 4096; bx = id & 127; by = id >> 7; }
  else { id -= 4096; W = W2; dst = w2t; K = 4096; N = 1024; bx = id & 31; by = id >> 5; }
  const int k0 = by * 32, n0 = bx * 32;
  const int tid = threadIdx.x;
  const int row = tid >> 3, c4 = (tid & 7) * 4;
  const float4 v = *(const float4*)&W[(size_t)(k0 + row) * N + n0 + c4];
  t[row][c4 + 0] = v.x; t[row][c4 + 1] = v.y;
  t[row][c4 + 2] = v.z; t[row][c4 + 3] = v.w;
  __syncthreads();
  u16x4 ov;
  #pragma unroll
  for (int j = 0; j < 4; ++j) ov[j] = f2bf(t[c4 + j][row]);
  *(u16x4*)&dst[(size_t)(n0 + row) * K + k0 + c4] = ov;
}

// ---------------- LayerNorm (fp32 in, bf16 out) ----------------
__global__ __launch_bounds__(256) void ln_kernel(
    const float* __restrict__ x, const float* __restrict__ g,
    const float* __restrict__ b, unsigned short* __restrict__ h)
{
  const int row = blockIdx.x, tid = threadIdx.x;
  const float4 v = ((const float4*)(x + (size_t)row * DM))[tid];
  float s  = v.x + v.y + v.z + v.w;
  float ss = v.x * v.x + v.y * v.y + v.z * v.z + v.w * v.w;
  #pragma unroll
  for (int m = 32; m >= 1; m >>= 1) {
    s  += __shfl_xor(s,  m, 64);
    ss += __shfl_xor(ss, m, 64);
  }
  __shared__ float red[8];
  const int w = tid >> 6, lane = tid & 63;
  if (lane == 0) { red[w] = s; red[4 + w] = ss; }
  __syncthreads();
  s  = red[0] + red[1] + red[2] + red[3];
  ss = red[4] + red[5] + red[6] + red[7];
  const float mu  = s * (1.f / DM);
  const float var = ss * (1.f / DM) - mu * mu;
  const float rs  = rsqrtf(var + 1e-5f);
  const float4 gv = ((const float4*)g)[tid];
  const float4 bv = ((const float4*)b)[tid];
  u16x4 o;
  o[0] = f2bf((v.x - mu) * rs * gv.x + bv.x);
  o[1] = f2bf((v.y - mu) * rs * gv.y + bv.y);
  o[2] = f2bf((v.z - mu) * rs * gv.z + bv.z);
  o[3] = f2bf((v.w - mu) * rs * gv.w + bv.w);
  ((u16x4*)(h + (size_t)row * DM))[tid] = o;
}

// ---------------- bias concat for all layers (bq*SC|bk|bv -> [4][3072]) ----------------
__global__ void concat3all(const float* __restrict__ a, const float* __restrict__ b,
                           const float* __restrict__ c, float* __restrict__ out)
{
  const int i = blockIdx.x * 256 + threadIdx.x;   // 0..4*3072-1
  const int l = i / 3072, r = i % 3072;
  out[i] = (r < 1024) ? a[l * 1024 + r] * SC
         : (r < 2048) ? b[l * 1024 + r - 1024]
                      : c[l * 1024 + r - 2048];
}

// ---------------- GEMM: C[M][N] = A@Bt^T + bias.  BK=64, dbuf stage-ahead ----------------
template<int RELU, int RESID, int VOUT>
__global__ __launch_bounds__(256) void gemm_bt(
    const unsigned short* __restrict__ A,
    const unsigned short* __restrict__ Bt,
    const float* __restrict__ bias,
    const float* __restrict__ res,
    float* __restrict__ outf,
    unsigned short* __restrict__ outb,
    unsigned short* __restrict__ vt,
    int M, int N, int K)
{
  __shared__ short Al[2][128 * 64];
  __shared__ short Bl[2][128 * 64];
  const int tid = threadIdx.x;
  const int w = tid >> 6, lane = tid & 63;
  const int m0 = blockIdx.y * 128, n0 = blockIdx.x * 128;
  const int wr = (w >> 1) * 64, wc = (w & 1) * 64;
  const int r16 = lane & 15, g4 = lane >> 4;
  const int niter = K >> 6;

  f32x4 acc[4][4];
  #pragma unroll
  for (int i = 0; i < 4; ++i)
    #pragma unroll
    for (int j = 0; j < 4; ++j) acc[i][j] = (f32x4){0.f, 0.f, 0.f, 0.f};

  #pragma unroll
  for (int i = 0; i < 4; ++i) {
    const int c = i * 256 + tid;
    const int ks = c >> 9, r = (c & 511) >> 2, off = (c & 3) * 8;
    gload16(&A[(size_t)(m0 + r) * K + ks * 32 + off], &Al[0][c * 8]);
    gload16(&Bt[(size_t)(n0 + r) * K + ks * 32 + off], &Bl[0][c * 8]);
  }

  for (int it = 0; it < niter; ++it) {
    const int buf = it & 1;
    __syncthreads();

    if (it + 1 < niter) {
      const int kt = (it + 1) << 6;
      #pragma unroll
      for (int i = 0; i < 4; ++i) {
        const int c = i * 256 + tid;
        const int ks = c >> 9, r = (c & 511) >> 2, off = (c & 3) * 8;
        gload16(&A[(size_t)(m0 + r) * K + kt + ks * 32 + off], &Al[buf ^ 1][c * 8]);
        gload16(&Bt[(size_t)(n0 + r) * K + kt + ks * 32 + off], &Bl[buf ^ 1][c * 8]);
      }
    }

    #pragma unroll
    for (int ks = 0; ks < 2; ++ks) {
      short8 af[4], bfr[4];
      #pragma unroll
      for (int mi = 0; mi < 4; ++mi)
        af[mi] = *(const short8*)&Al[buf][ks * 4096 + (wr + mi * 16 + r16) * 32 + g4 * 8];
      #pragma unroll
      for (int ni = 0; ni < 4; ++ni)
        bfr[ni] = *(const short8*)&Bl[buf][ks * 4096 + (wc + ni * 16 + r16) * 32 + g4 * 8];
      #pragma unroll
      for (int mi = 0; mi < 4; ++mi)
        #pragma unroll
        for (int ni = 0; ni < 4; ++ni)
          acc[mi][ni] = __builtin_amdgcn_mfma_f32_16x16x32_bf16(af[mi], bfr[ni], acc[mi][ni], 0, 0, 0);
    }
  }

  #pragma unroll
  for (int ni = 0; ni < 4; ++ni) {
    const int col = n0 + wc + ni * 16 + r16;
    const float bv = bias[col];
    #pragma unroll
    for (int mi = 0; mi < 4; ++mi) {
      const int row = m0 + wr + mi * 16 + g4 * 4;
      float v4[4];
      #pragma unroll
      for (int j = 0; j < 4; ++j) {
        float v = acc[mi][ni][j] + bv;
        if (RELU) v = fmaxf(v, 0.f);
        v4[j] = v;
      }
      if (VOUT && col >= 2048) {
        const int hh = (col - 2048) >> 6, dd = (col - 2048) & 63;
        const int bb = row >> 11, ss = row & 2047;
        u16x4 pv;
        #pragma unroll
        for (int j = 0; j < 4; ++j) pv[j] = f2bf(v4[j]);
        *(u16x4*)&vt[(((size_t)bb * 16 + hh) * 64 + dd) * SLEN + ss] = pv;
      } else {
        #pragma unroll
        for (int j = 0; j < 4; ++j) {
          const size_t idx = (size_t)(row + j) * N + col;
          if (RESID) outf[idx] = res[idx] + v4[j];
          else       outb[idx] = f2bf(v4[j]);
        }
      }
    }
  }
}

// ---------------- GEMM N-tile=64 (O-proj / FFN2): BK=64, dbuf stage-ahead ----------------
__global__ __launch_bounds__(256) void gemm_n64(
    const unsigned short* __restrict__ A,
    const unsigned short* __restrict__ Bt,
    const float* __restrict__ bias,
    const float* __restrict__ res,
    float* __restrict__ outf,
    int M, int N, int K)
{
  __shared__ short Al[2][128 * 64];
  __shared__ short Bl[2][64 * 64];
  const int tid = threadIdx.x;
  const int w = tid >> 6, lane = tid & 63;
  const int m0 = blockIdx.y * 128, n0 = blockIdx.x * 64;
  const int wr = (w >> 1) * 64, wc = (w & 1) * 32;
  const int r16 = lane & 15, g4 = lane >> 4;
  const int niter = K >> 6;

  f32x4 acc[4][2];
  #pragma unroll
  for (int i = 0; i < 4; ++i)
    #pragma unroll
    for (int j = 0; j < 2; ++j) acc[i][j] = (f32x4){0.f, 0.f, 0.f, 0.f};

  #pragma unroll
  for (int i = 0; i < 4; ++i) {
    const int c = i * 256 + tid;
    const int ks = c >> 9, r = (c & 511) >> 2, off = (c & 3) * 8;
    gload16(&A[(size_t)(m0 + r) * K + ks * 32 + off], &Al[0][c * 8]);
  }
  #pragma unroll
  for (int i = 0; i < 2; ++i) {
    const int c = i * 256 + tid;
    const int ks = c >> 8, r = (c & 255) >> 2, off = (c & 3) * 8;
    gload16(&Bt[(size_t)(n0 + r) * K + ks * 32 + off], &Bl[0][c * 8]);
  }

  for (int it = 0; it < niter; ++it) {
    const int buf = it & 1;
    __syncthreads();

    if (it + 1 < niter) {
      const int kt = (it + 1) << 6;
      #pragma unroll
      for (int i = 0; i < 4; ++i) {
        const int c = i * 256 + tid;
        const int ks = c >> 9, r = (c & 511) >> 2, off = (c & 3) * 8;
        gload16(&A[(size_t)(m0 + r) * K + kt + ks * 32 + off], &Al[buf ^ 1][c * 8]);
      }
      #pragma unroll
      for (int i = 0; i < 2; ++i) {
        const int c = i * 256 + tid;
        const int ks = c >> 8, r = (c & 255) >> 2, off = (c & 3) * 8;
        gload16(&Bt[(size_t)(n0 + r) * K + kt + ks * 32 + off], &Bl[buf ^ 1][c * 8]);
      }
    }

    short8 af[4][2], bfr[2][2];
    #pragma unroll
    for (int mi = 0; mi < 4; ++mi)
      #pragma unroll
      for (int ks = 0; ks < 2; ++ks)
        af[mi][ks] = *(const short8*)&Al[buf][ks * 4096 + (wr + mi * 16 + r16) * 32 + g4 * 8];
    #pragma unroll
    for (int ni = 0; ni < 2; ++ni)
      #pragma unroll
      for (int ks = 0; ks < 2; ++ks)
        bfr[ni][ks] = *(const short8*)&Bl[buf][ks * 2048 + (wc + ni * 16 + r16) * 32 + g4 * 8];
    #pragma unroll
    for (int ks = 0; ks < 2; ++ks)
      #pragma unroll
      for (int mi = 0; mi < 4; ++mi)
        #pragma unroll
        for (int ni = 0; ni < 2; ++ni)
          acc[mi][ni] = __builtin_amdgcn_mfma_f32_16x16x32_bf16(af[mi][ks], bfr[ni][ks], acc[mi][ni], 0, 0, 0);
  }

  #pragma unroll
  for (int ni = 0; ni < 2; ++ni) {
    const int col = n0 + wc + ni * 16 + r16;
    const float bv = bias[col];
    #pragma unroll
    for (int mi = 0; mi < 4; ++mi) {
      const int row = m0 + wr + mi * 16 + g4 * 4;
      #pragma unroll
      for (int j = 0; j < 4; ++j) {
        const size_t idx = (size_t)(row + j) * N + col;
        outf[idx] = res[idx] + acc[mi][ni][j] + bv;
      }
    }
  }
}

// ---------------- Flash attention v10: gload_lds staging + source-XOR swizzle ----------------
// LDS[row][c] = G[row][c ^ (row&7)] (chunks of 8 bf16); reads apply the same XOR.
#define LSTR 64
#define PSTR 68
#define NT   (SLEN / 64)
__global__ __launch_bounds__(256) void attn_kernel(
    const unsigned short* __restrict__ qkv,   // [B*S][3072] (q*SC|k|v)
    const unsigned short* __restrict__ vt,    // [B*H][64][2048]
    unsigned short* __restrict__ o)           // [B*S][1024]
{
  __shared__ short Kl[2][64 * LSTR];
  __shared__ short Vl[2][64 * LSTR];   // transposed: [d][key]
  __shared__ short Pl[128 * PSTR];     // per-wave 32-row regions
  const int tid = threadIdx.x;
  const int w = tid >> 6, lane = tid & 63;
  const int r16 = lane & 15, g4 = lane >> 4;
  const int qt = blockIdx.x;
  const int bh = blockIdx.y;
  const int hh = bh & 15;
  const size_t rowbase = (size_t)(bh >> 4) * SLEN;
  const short* qp = (const short*)qkv;
  const short* vp = (const short*)(vt + (size_t)bh * 64 * SLEN);

  short8 qf[2][2];
  #pragma unroll
  for (int mi = 0; mi < 2; ++mi) {
    const size_t qrow = rowbase + qt * 128 + w * 32 + mi * 16 + r16;
    #pragma unroll
    for (int kk = 0; kk < 2; ++kk)
      qf[mi][kk] = *(const short8*)&qp[qrow * QKVLD + hh * 64 + kk * 32 + g4 * 8];
  }

  short8 ones;
  #pragma unroll
  for (int i = 0; i < 8; ++i) ones[i] = (short)0x3F80;  // bf16 1.0

  // staging: thread handles rows srow, srow+32; chunk sc; source chunk XOR-swizzled
  const int srow = tid >> 3;
  const int sc   = tid & 7;
  const int scx  = sc ^ (srow & 7);
  const int rxor = (r16 & 7);   // read-side XOR term

  // prologue: tile 0 -> buf 0 (direct global->LDS)
  #pragma unroll
  for (int i = 0; i < 2; ++i) {
    const int row = srow + i * 32;
    gload16(&qp[(rowbase + row) * QKVLD + 1024 + hh * 64 + scx * 8], &Kl[0][row * LSTR + sc * 8]);
    gload16(&vp[(size_t)row * SLEN + scx * 8], &Vl[0][row * LSTR + sc * 8]);
  }

  f32x4 oacc[2][4];
  f32x4 l_vec[2];
  float m_prev[2][4];
  #pragma unroll
  for (int mi = 0; mi < 2; ++mi) {
    l_vec[mi] = (f32x4){0.f, 0.f, 0.f, 0.f};
    #pragma unroll
    for (int hf = 0; hf < 4; ++hf) oacc[mi][hf] = (f32x4){0.f, 0.f, 0.f, 0.f};
    #pragma unroll
    for (int j = 0; j < 4; ++j) m_prev[mi][j] = -1e30f;
  }

  for (int kt = 0; kt < NT; ++kt) {
    const int cur = kt & 1;
    __syncthreads();   // drains this tile's gloads; protects buf^1 reuse

    // issue NEXT tile's loads straight into the other buffer
    if (kt + 1 < NT) {
      #pragma unroll
      for (int i = 0; i < 2; ++i) {
        const int row = srow + i * 32;
        gload16(&qp[(rowbase + (kt + 1) * 64 + row) * QKVLD + 1024 + hh * 64 + scx * 8],
                &Kl[cur ^ 1][row * LSTR + sc * 8]);
        gload16(&vp[(size_t)row * SLEN + (kt + 1) * 64 + scx * 8],
                &Vl[cur ^ 1][row * LSTR + sc * 8]);
      }
    }

    // ---- QK^T (scores pre-scaled to log2 domain) ----
    short8 kfr[4][2];
    #pragma unroll
    for (int kf = 0; kf < 4; ++kf)
      #pragma unroll
      for (int kk = 0; kk < 2; ++kk)
        kfr[kf][kk] = *(const short8*)&Kl[cur][(kf * 16 + r16) * LSTR + ((kk * 4 + g4) ^ rxor) * 8];
    f32x4 sf[2][4];
    #pragma unroll
    for (int mi = 0; mi < 2; ++mi)
      #pragma unroll
      for (int kf = 0; kf < 4; ++kf) {
        f32x4 a = (f32x4){0.f, 0.f, 0.f, 0.f};
        #pragma unroll
        for (int kk = 0; kk < 2; ++kk)
          a = __builtin_amdgcn_mfma_f32_16x16x32_bf16(qf[mi][kk], kfr[kf][kk], a, 0, 0, 0);
        sf[mi][kf] = a;
      }

    // ---- online softmax max-tracking with defer (THR=8, log2 domain) ----
    float tmv[2][4];
    bool need = false;
    #pragma unroll
    for (int mi = 0; mi < 2; ++mi)
      #pragma unroll
      for (int j = 0; j < 4; ++j) {
        float tm = fmaxf(fmaxf(sf[mi][0][j], sf[mi][1][j]), fmaxf(sf[mi][2][j], sf[mi][3][j]));
        #pragma unroll
        for (int mm = 8; mm >= 1; mm >>= 1) tm = fmaxf(tm, __shfl_xor(tm, mm, 64));
        tmv[mi][j] = tm;
        need = need || (tm > m_prev[mi][j] + 8.f);
      }
    if (__ballot(need)) {
      #pragma unroll
      for (int mi = 0; mi < 2; ++mi)
        #pragma unroll
        for (int j = 0; j < 4; ++j) {
          const float mn = fmaxf(m_prev[mi][j], tmv[mi][j]);
          const float fs = __builtin_amdgcn_exp2f(m_prev[mi][j] - mn);
          m_prev[mi][j] = mn;
          l_vec[mi][j] *= fs;
          #pragma unroll
          for (int hf = 0; hf < 4; ++hf) oacc[mi][hf][j] *= fs;
        }
    }
    #pragma unroll
    for (int mi = 0; mi < 2; ++mi)
      #pragma unroll
      for (int kf = 0; kf < 4; ++kf)
        #pragma unroll
        for (int j = 0; j < 4; ++j) {
          const float p = __builtin_amdgcn_exp2f(sf[mi][kf][j] - m_prev[mi][j]);
          Pl[(w * 32 + mi * 16 + g4 * 4 + j) * PSTR + kf * 16 + r16] = (short)f2bf(p);
        }

    // ---- PV + row-sums ----
    short8 vf[2][4];
    #pragma unroll
    for (int kk = 0; kk < 2; ++kk)
      #pragma unroll
      for (int hf = 0; hf < 4; ++hf)
        vf[kk][hf] = *(const short8*)&Vl[cur][(hf * 16 + r16) * LSTR + ((kk * 4 + g4) ^ rxor) * 8];
    short8 pf[2][2];
    #pragma unroll
    for (int mi = 0; mi < 2; ++mi)
      #pragma unroll
      for (int kk = 0; kk < 2; ++kk)
        pf[mi][kk] = *(const short8*)&Pl[(w * 32 + mi * 16 + r16) * PSTR + kk * 32 + g4 * 8];
    #pragma unroll
    for (int mi = 0; mi < 2; ++mi) {
      #pragma unroll
      for (int kk = 0; kk < 2; ++kk) {
        l_vec[mi] = __builtin_amdgcn_mfma_f32_16x16x32_bf16(pf[mi][kk], ones, l_vec[mi], 0, 0, 0);
        #pragma unroll
        for (int hf = 0; hf < 4; ++hf)
          oacc[mi][hf] = __builtin_amdgcn_mfma_f32_16x16x32_bf16(pf[mi][kk], vf[kk][hf], oacc[mi][hf], 0, 0, 0);
      }
    }
  }

  #pragma unroll
  for (int mi = 0; mi < 2; ++mi)
    #pragma unroll
    for (int j = 0; j < 4; ++j) {
      const float rl = 1.f / l_vec[mi][j];
      const size_t orow = rowbase + qt * 128 + w * 32 + mi * 16 + g4 * 4 + j;
      #pragma unroll
      for (int hf = 0; hf < 4; ++hf)
        o[orow * DM + hh * 64 + hf * 16 + r16] = f2bf(oacc[mi][hf][j] * rl);
    }
}

// ---------------- launcher ----------------
extern "C" void kernel_launch(void* const* d_in, const int* in_sizes, int n_in,
                              void* d_out, int out_size, void* d_ws, size_t ws_size,
                              hipStream_t stream) {
  const float* x_in = (const float*)d_in[0];
  const float* Wq = (const float*)d_in[1];  const float* bq = (const float*)d_in[2];
  const float* Wk = (const float*)d_in[3];  const float* bk = (const float*)d_in[4];
  const float* Wv = (const float*)d_in[5];  const float* bv = (const float*)d_in[6];
  const float* Wo = (const float*)d_in[7];  const float* bo = (const float*)d_in[8];
  const float* W1 = (const float*)d_in[9];  const float* b1 = (const float*)d_in[10];
  const float* W2 = (const float*)d_in[11]; const float* b2 = (const float*)d_in[12];
  const float* ln1g = (const float*)d_in[13]; const float* ln1b = (const float*)d_in[14];
  const float* ln2g = (const float*)d_in[15]; const float* ln2b = (const float*)d_in[16];

  const size_t MB = 1u << 20;
  char* ws = (char*)d_ws;
  float*          x   = (float*)(ws + 0);                 // 16 MB fp32 residual
  unsigned short* h   = (unsigned short*)(ws + 16 * MB);  // 8 MB bf16 LN out
  unsigned short* qkv = (unsigned short*)(ws + 24 * MB);  // 24 MB bf16 [4096][3072]
  unsigned short* ob  = (unsigned short*)(ws + 48 * MB);  // 8 MB bf16 attn out
  unsigned short* f1  = (unsigned short*)(ws + 56 * MB);  // 32 MB bf16 ffn mid
  unsigned short* vt  = f1;                               // V^T reuses f1 (disjoint in time)
  unsigned short* wt  = (unsigned short*)(ws + 88 * MB);  // 8 MB bf16 transposed W (QKVO / W1)
  unsigned short* w2t = qkv;                              // W2^T parks in dead qkv buffer
  float*          b3  = (float*)(ws + 96 * MB);           // 48 KB qkv bias (all layers)

  concat3all<<<48, 256, 0, stream>>>(bq, bk, bv, b3);

  for (int i = 0; i < 4; ++i) {
    const size_t DD = (size_t)DM * DM;
    const float* xin  = (i == 0) ? x_in : x;              // layer-0 reads input directly
    float*       xout = (i == 3) ? (float*)d_out : x;     // layer-3 FFN2 writes output directly
    // --- attention sublayer ---
    tr_qkvo<<<dim3(32, 32, 4), 256, 0, stream>>>(
        Wq + i * DD, Wk + i * DD, Wv + i * DD, Wo + i * DD, wt);
    ln_kernel<<<MROWS, 256, 0, stream>>>(xin, ln1g + i * DM, ln1b + i * DM, h);
    gemm_bt<0, 0, 1><<<dim3(QKVLD / 128, MROWS / 128), 256, 0, stream>>>(
        h, wt, b3 + i * QKVLD, nullptr, nullptr, qkv, vt, MROWS, QKVLD, DM);
    attn_kernel<<<dim3(SLEN / 128, 32), 256, 0, stream>>>(qkv, vt, ob);
    gemm_n64<<<dim3(DM / 64, MROWS / 128), 256, 0, stream>>>(
        ob, wt + (size_t)3 * 1024 * 1024, bo + i * DM, xin, x, MROWS, DM, DM);
    // --- FFN sublayer ---
    tr_w12<<<8192, 256, 0, stream>>>(W1 + i * 4 * DD, W2 + i * 4 * DD, wt, w2t);
    ln_kernel<<<MROWS, 256, 0, stream>>>(x, ln2g + i * DM, ln2b + i * DM, h);
    gemm_bt<1, 0, 0><<<dim3(4 * DM / 128, MROWS / 128), 256, 0, stream>>>(
        h, wt, b1 + i * 4 * DM, nullptr, nullptr, f1, nullptr, MROWS, 4 * DM, DM);
    gemm_n64<<<dim3(DM / 64, MROWS / 128), 256, 0, stream>>>(
        f1, w2t, b2 + i * DM, x, xout, MROWS, DM, 4 * DM);
  }
}

// Round 15
// 1142.627 us; speedup vs baseline: 1.0096x; 1.0096x over previous
//
#include <hip/hip_runtime.h>
#include <hip/hip_bf16.h>

#define DM 1024
#define SLEN 2048
#define MROWS 4096   // B*S
#define QKVLD 3072
#define SC 0.18033688f   // 0.125 * log2(e), folded into Wq/bq

typedef short  short8 __attribute__((ext_vector_type(8)));
typedef float  f32x4  __attribute__((ext_vector_type(4)));
typedef unsigned short u16x4 __attribute__((ext_vector_type(4)));

__device__ __forceinline__ unsigned short f2bf(float f) {
  __hip_bfloat16 h = __float2bfloat16(f);
  return __builtin_bit_cast(unsigned short, h);
}

__device__ __forceinline__ void gload16(const void* g, void* l) {
  __builtin_amdgcn_global_load_lds(
      (const __attribute__((address_space(1))) unsigned int*)g,
      (__attribute__((address_space(3))) unsigned int*)l, 16, 0, 0);
}

// ---------------- Wq/Wk/Wv/Wo transpose+cvt in ONE launch (grid.z picks) ----------------
__global__ __launch_bounds__(256) void tr_qkvo(
    const float* __restrict__ Wq, const float* __restrict__ Wk,
    const float* __restrict__ Wv, const float* __restrict__ Wo,
    unsigned short* __restrict__ wt)
{
  __shared__ float t[32][33];
  const int z = blockIdx.z;
  const float* W = (z == 0) ? Wq : (z == 1) ? Wk : (z == 2) ? Wv : Wo;
  const float scale = (z == 0) ? SC : 1.f;
  unsigned short* dst = wt + (size_t)z * 1024 * 1024;
  const int k0 = blockIdx.y * 32, n0 = blockIdx.x * 32;
  const int tid = threadIdx.x;
  const int row = tid >> 3, c4 = (tid & 7) * 4;
  const float4 v = *(const float4*)&W[(size_t)(k0 + row) * DM + n0 + c4];
  t[row][c4 + 0] = v.x; t[row][c4 + 1] = v.y;
  t[row][c4 + 2] = v.z; t[row][c4 + 3] = v.w;
  __syncthreads();
  u16x4 ov;
  #pragma unroll
  for (int j = 0; j < 4; ++j) ov[j] = f2bf(t[c4 + j][row] * scale);
  *(u16x4*)&dst[(size_t)(n0 + row) * DM + k0 + c4] = ov;
}

// ---------------- W1 + W2 transpose+cvt in ONE launch ----------------
__global__ __launch_bounds__(256) void tr_w12(
    const float* __restrict__ W1, const float* __restrict__ W2,
    unsigned short* __restrict__ w1t, unsigned short* __restrict__ w2t)
{
  __shared__ float t[32][33];
  int id = blockIdx.x;
  const float* W; unsigned short* dst; int K, N, bx, by;
  if (id < 4096) { W = W1; dst = w1t; K = 1024; N = 4096; bx = id & 127; by = id >> 7; }
  else { id -= 4096; W = W2; dst = w2t; K = 4096; N = 1024; bx = id & 31; by = id >> 5; }
  const int k0 = by * 32, n0 = bx * 32;
  const int tid = threadIdx.x;
  const int row = tid >> 3, c4 = (tid & 7) * 4;
  const float4 v = *(const float4*)&W[(size_t)(k0 + row) * N + n0 + c4];
  t[row][c4 + 0] = v.x; t[row][c4 + 1] = v.y;
  t[row][c4 + 2] = v.z; t[row][c4 + 3] = v.w;
  __syncthreads();
  u16x4 ov;
  #pragma unroll
  for (int j = 0; j < 4; ++j) ov[j] = f2bf(t[c4 + j][row]);
  *(u16x4*)&dst[(size_t)(n0 + row) * K + k0 + c4] = ov;
}

// ---------------- LayerNorm (fp32 in, bf16 out) ----------------
__global__ __launch_bounds__(256) void ln_kernel(
    const float* __restrict__ x, const float* __restrict__ g,
    const float* __restrict__ b, unsigned short* __restrict__ h)
{
  const int row = blockIdx.x, tid = threadIdx.x;
  const float4 v = ((const float4*)(x + (size_t)row * DM))[tid];
  float s  = v.x + v.y + v.z + v.w;
  float ss = v.x * v.x + v.y * v.y + v.z * v.z + v.w * v.w;
  #pragma unroll
  for (int m = 32; m >= 1; m >>= 1) {
    s  += __shfl_xor(s,  m, 64);
    ss += __shfl_xor(ss, m, 64);
  }
  __shared__ float red[8];
  const int w = tid >> 6, lane = tid & 63;
  if (lane == 0) { red[w] = s; red[4 + w] = ss; }
  __syncthreads();
  s  = red[0] + red[1] + red[2] + red[3];
  ss = red[4] + red[5] + red[6] + red[7];
  const float mu  = s * (1.f / DM);
  const float var = ss * (1.f / DM) - mu * mu;
  const float rs  = rsqrtf(var + 1e-5f);
  const float4 gv = ((const float4*)g)[tid];
  const float4 bv = ((const float4*)b)[tid];
  u16x4 o;
  o[0] = f2bf((v.x - mu) * rs * gv.x + bv.x);
  o[1] = f2bf((v.y - mu) * rs * gv.y + bv.y);
  o[2] = f2bf((v.z - mu) * rs * gv.z + bv.z);
  o[3] = f2bf((v.w - mu) * rs * gv.w + bv.w);
  ((u16x4*)(h + (size_t)row * DM))[tid] = o;
}

// ---------------- bias concat for all layers (bq*SC|bk|bv -> [4][3072]) ----------------
__global__ void concat3all(const float* __restrict__ a, const float* __restrict__ b,
                           const float* __restrict__ c, float* __restrict__ out)
{
  const int i = blockIdx.x * 256 + threadIdx.x;   // 0..4*3072-1
  const int l = i / 3072, r = i % 3072;
  out[i] = (r < 1024) ? a[l * 1024 + r] * SC
         : (r < 2048) ? b[l * 1024 + r - 1024]
                      : c[l * 1024 + r - 2048];
}

// ---------------- GEMM: C[M][N] = A@Bt^T + bias.  BK=64, dbuf stage-ahead ----------------
template<int RELU, int RESID, int VOUT>
__global__ __launch_bounds__(256) void gemm_bt(
    const unsigned short* __restrict__ A,
    const unsigned short* __restrict__ Bt,
    const float* __restrict__ bias,
    const float* __restrict__ res,
    float* __restrict__ outf,
    unsigned short* __restrict__ outb,
    unsigned short* __restrict__ vt,
    int M, int N, int K)
{
  __shared__ short Al[2][128 * 64];
  __shared__ short Bl[2][128 * 64];
  const int tid = threadIdx.x;
  const int w = tid >> 6, lane = tid & 63;
  const int m0 = blockIdx.y * 128, n0 = blockIdx.x * 128;
  const int wr = (w >> 1) * 64, wc = (w & 1) * 64;
  const int r16 = lane & 15, g4 = lane >> 4;
  const int niter = K >> 6;

  f32x4 acc[4][4];
  #pragma unroll
  for (int i = 0; i < 4; ++i)
    #pragma unroll
    for (int j = 0; j < 4; ++j) acc[i][j] = (f32x4){0.f, 0.f, 0.f, 0.f};

  #pragma unroll
  for (int i = 0; i < 4; ++i) {
    const int c = i * 256 + tid;
    const int ks = c >> 9, r = (c & 511) >> 2, off = (c & 3) * 8;
    gload16(&A[(size_t)(m0 + r) * K + ks * 32 + off], &Al[0][c * 8]);
    gload16(&Bt[(size_t)(n0 + r) * K + ks * 32 + off], &Bl[0][c * 8]);
  }

  for (int it = 0; it < niter; ++it) {
    const int buf = it & 1;
    __syncthreads();

    if (it + 1 < niter) {
      const int kt = (it + 1) << 6;
      #pragma unroll
      for (int i = 0; i < 4; ++i) {
        const int c = i * 256 + tid;
        const int ks = c >> 9, r = (c & 511) >> 2, off = (c & 3) * 8;
        gload16(&A[(size_t)(m0 + r) * K + kt + ks * 32 + off], &Al[buf ^ 1][c * 8]);
        gload16(&Bt[(size_t)(n0 + r) * K + kt + ks * 32 + off], &Bl[buf ^ 1][c * 8]);
      }
    }

    #pragma unroll
    for (int ks = 0; ks < 2; ++ks) {
      short8 af[4], bfr[4];
      #pragma unroll
      for (int mi = 0; mi < 4; ++mi)
        af[mi] = *(const short8*)&Al[buf][ks * 4096 + (wr + mi * 16 + r16) * 32 + g4 * 8];
      #pragma unroll
      for (int ni = 0; ni < 4; ++ni)
        bfr[ni] = *(const short8*)&Bl[buf][ks * 4096 + (wc + ni * 16 + r16) * 32 + g4 * 8];
      #pragma unroll
      for (int mi = 0; mi < 4; ++mi)
        #pragma unroll
        for (int ni = 0; ni < 4; ++ni)
          acc[mi][ni] = __builtin_amdgcn_mfma_f32_16x16x32_bf16(af[mi], bfr[ni], acc[mi][ni], 0, 0, 0);
    }
  }

  #pragma unroll
  for (int ni = 0; ni < 4; ++ni) {
    const int col = n0 + wc + ni * 16 + r16;
    const float bv = bias[col];
    #pragma unroll
    for (int mi = 0; mi < 4; ++mi) {
      const int row = m0 + wr + mi * 16 + g4 * 4;
      float v4[4];
      #pragma unroll
      for (int j = 0; j < 4; ++j) {
        float v = acc[mi][ni][j] + bv;
        if (RELU) v = fmaxf(v, 0.f);
        v4[j] = v;
      }
      if (VOUT && col >= 2048) {
        const int hh = (col - 2048) >> 6, dd = (col - 2048) & 63;
        const int bb = row >> 11, ss = row & 2047;
        u16x4 pv;
        #pragma unroll
        for (int j = 0; j < 4; ++j) pv[j] = f2bf(v4[j]);
        *(u16x4*)&vt[(((size_t)bb * 16 + hh) * 64 + dd) * SLEN + ss] = pv;
      } else {
        #pragma unroll
        for (int j = 0; j < 4; ++j) {
          const size_t idx = (size_t)(row + j) * N + col;
          if (RESID) outf[idx] = res[idx] + v4[j];
          else       outb[idx] = f2bf(v4[j]);
        }
      }
    }
  }
}

// ---------------- GEMM N-tile=64 (O-proj / FFN2): BK=64, dbuf stage-ahead ----------------
__global__ __launch_bounds__(256) void gemm_n64(
    const unsigned short* __restrict__ A,
    const unsigned short* __restrict__ Bt,
    const float* __restrict__ bias,
    const float* __restrict__ res,
    float* __restrict__ outf,
    int M, int N, int K)
{
  __shared__ short Al[2][128 * 64];
  __shared__ short Bl[2][64 * 64];
  const int tid = threadIdx.x;
  const int w = tid >> 6, lane = tid & 63;
  const int m0 = blockIdx.y * 128, n0 = blockIdx.x * 64;
  const int wr = (w >> 1) * 64, wc = (w & 1) * 32;
  const int r16 = lane & 15, g4 = lane >> 4;
  const int niter = K >> 6;

  f32x4 acc[4][2];
  #pragma unroll
  for (int i = 0; i < 4; ++i)
    #pragma unroll
    for (int j = 0; j < 2; ++j) acc[i][j] = (f32x4){0.f, 0.f, 0.f, 0.f};

  #pragma unroll
  for (int i = 0; i < 4; ++i) {
    const int c = i * 256 + tid;
    const int ks = c >> 9, r = (c & 511) >> 2, off = (c & 3) * 8;
    gload16(&A[(size_t)(m0 + r) * K + ks * 32 + off], &Al[0][c * 8]);
  }
  #pragma unroll
  for (int i = 0; i < 2; ++i) {
    const int c = i * 256 + tid;
    const int ks = c >> 8, r = (c & 255) >> 2, off = (c & 3) * 8;
    gload16(&Bt[(size_t)(n0 + r) * K + ks * 32 + off], &Bl[0][c * 8]);
  }

  for (int it = 0; it < niter; ++it) {
    const int buf = it & 1;
    __syncthreads();

    if (it + 1 < niter) {
      const int kt = (it + 1) << 6;
      #pragma unroll
      for (int i = 0; i < 4; ++i) {
        const int c = i * 256 + tid;
        const int ks = c >> 9, r = (c & 511) >> 2, off = (c & 3) * 8;
        gload16(&A[(size_t)(m0 + r) * K + kt + ks * 32 + off], &Al[buf ^ 1][c * 8]);
      }
      #pragma unroll
      for (int i = 0; i < 2; ++i) {
        const int c = i * 256 + tid;
        const int ks = c >> 8, r = (c & 255) >> 2, off = (c & 3) * 8;
        gload16(&Bt[(size_t)(n0 + r) * K + kt + ks * 32 + off], &Bl[buf ^ 1][c * 8]);
      }
    }

    short8 af[4][2], bfr[2][2];
    #pragma unroll
    for (int mi = 0; mi < 4; ++mi)
      #pragma unroll
      for (int ks = 0; ks < 2; ++ks)
        af[mi][ks] = *(const short8*)&Al[buf][ks * 4096 + (wr + mi * 16 + r16) * 32 + g4 * 8];
    #pragma unroll
    for (int ni = 0; ni < 2; ++ni)
      #pragma unroll
      for (int ks = 0; ks < 2; ++ks)
        bfr[ni][ks] = *(const short8*)&Bl[buf][ks * 2048 + (wc + ni * 16 + r16) * 32 + g4 * 8];
    #pragma unroll
    for (int ks = 0; ks < 2; ++ks)
      #pragma unroll
      for (int mi = 0; mi < 4; ++mi)
        #pragma unroll
        for (int ni = 0; ni < 2; ++ni)
          acc[mi][ni] = __builtin_amdgcn_mfma_f32_16x16x32_bf16(af[mi][ks], bfr[ni][ks], acc[mi][ni], 0, 0, 0);
  }

  #pragma unroll
  for (int ni = 0; ni < 2; ++ni) {
    const int col = n0 + wc + ni * 16 + r16;
    const float bv = bias[col];
    #pragma unroll
    for (int mi = 0; mi < 4; ++mi) {
      const int row = m0 + wr + mi * 16 + g4 * 4;
      #pragma unroll
      for (int j = 0; j < 4; ++j) {
        const size_t idx = (size_t)(row + j) * N + col;
        outf[idx] = res[idx] + acc[mi][ni][j] + bv;
      }
    }
  }
}

// ---------------- Flash attention v7 (best measured: reg-staged, LSTR=68) ----------------
#define LSTR 68
#define PSTR 68
#define NT   (SLEN / 64)
__global__ __launch_bounds__(256) void attn_kernel(
    const unsigned short* __restrict__ qkv,   // [B*S][3072] (q*SC|k|v)
    const unsigned short* __restrict__ vt,    // [B*H][64][2048]
    unsigned short* __restrict__ o)           // [B*S][1024]
{
  __shared__ short Kl[2][64 * LSTR];
  __shared__ short Vl[2][64 * LSTR];   // transposed: [d][key]
  __shared__ short Pl[128 * PSTR];     // per-wave 32-row regions
  const int tid = threadIdx.x;
  const int w = tid >> 6, lane = tid & 63;
  const int r16 = lane & 15, g4 = lane >> 4;
  const int qt = blockIdx.x;
  const int bh = blockIdx.y;
  const int hh = bh & 15;
  const size_t rowbase = (size_t)(bh >> 4) * SLEN;
  const short* qp = (const short*)qkv;
  const short* vp = (const short*)(vt + (size_t)bh * 64 * SLEN);

  short8 qf[2][2];
  #pragma unroll
  for (int mi = 0; mi < 2; ++mi) {
    const size_t qrow = rowbase + qt * 128 + w * 32 + mi * 16 + r16;
    #pragma unroll
    for (int kk = 0; kk < 2; ++kk)
      qf[mi][kk] = *(const short8*)&qp[qrow * QKVLD + hh * 64 + kk * 32 + g4 * 8];
  }

  short8 ones;
  #pragma unroll
  for (int i = 0; i < 8; ++i) ones[i] = (short)0x3F80;  // bf16 1.0

  const int srow = tid >> 3;
  const int soff = (tid & 7) * 8;
  short8 kreg[2], vreg[2];

  #pragma unroll
  for (int i = 0; i < 2; ++i) {
    const int row = srow + i * 32;
    kreg[i] = *(const short8*)&qp[(rowbase + row) * QKVLD + 1024 + hh * 64 + soff];
    vreg[i] = *(const short8*)&vp[(size_t)row * SLEN + soff];
  }
  #pragma unroll
  for (int i = 0; i < 2; ++i) {
    const int row = srow + i * 32;
    *(short8*)&Kl[0][row * LSTR + soff] = kreg[i];
    *(short8*)&Vl[0][row * LSTR + soff] = vreg[i];
  }

  f32x4 oacc[2][4];
  f32x4 l_vec[2];
  float m_prev[2][4];
  #pragma unroll
  for (int mi = 0; mi < 2; ++mi) {
    l_vec[mi] = (f32x4){0.f, 0.f, 0.f, 0.f};
    #pragma unroll
    for (int hf = 0; hf < 4; ++hf) oacc[mi][hf] = (f32x4){0.f, 0.f, 0.f, 0.f};
    #pragma unroll
    for (int j = 0; j < 4; ++j) m_prev[mi][j] = -1e30f;
  }

  for (int kt = 0; kt < NT; ++kt) {
    const int cur = kt & 1;
    if (kt + 1 < NT) {
      #pragma unroll
      for (int i = 0; i < 2; ++i) {
        const int row = srow + i * 32;
        kreg[i] = *(const short8*)&qp[(rowbase + (kt + 1) * 64 + row) * QKVLD + 1024 + hh * 64 + soff];
        vreg[i] = *(const short8*)&vp[(size_t)row * SLEN + (kt + 1) * 64 + soff];
      }
    }
    __syncthreads();

    // ---- QK^T (scores pre-scaled to log2 domain) ----
    short8 kfr[4][2];
    #pragma unroll
    for (int kf = 0; kf < 4; ++kf)
      #pragma unroll
      for (int kk = 0; kk < 2; ++kk)
        kfr[kf][kk] = *(const short8*)&Kl[cur][(kf * 16 + r16) * LSTR + kk * 32 + g4 * 8];
    f32x4 sf[2][4];
    #pragma unroll
    for (int mi = 0; mi < 2; ++mi)
      #pragma unroll
      for (int kf = 0; kf < 4; ++kf) {
        f32x4 a = (f32x4){0.f, 0.f, 0.f, 0.f};
        #pragma unroll
        for (int kk = 0; kk < 2; ++kk)
          a = __builtin_amdgcn_mfma_f32_16x16x32_bf16(qf[mi][kk], kfr[kf][kk], a, 0, 0, 0);
        sf[mi][kf] = a;
      }

    // ---- online softmax max-tracking with defer (THR=8, log2 domain) ----
    float tmv[2][4];
    bool need = false;
    #pragma unroll
    for (int mi = 0; mi < 2; ++mi)
      #pragma unroll
      for (int j = 0; j < 4; ++j) {
        float tm = fmaxf(fmaxf(sf[mi][0][j], sf[mi][1][j]), fmaxf(sf[mi][2][j], sf[mi][3][j]));
        #pragma unroll
        for (int mm = 8; mm >= 1; mm >>= 1) tm = fmaxf(tm, __shfl_xor(tm, mm, 64));
        tmv[mi][j] = tm;
        need = need || (tm > m_prev[mi][j] + 8.f);
      }
    if (__ballot(need)) {
      #pragma unroll
      for (int mi = 0; mi < 2; ++mi)
        #pragma unroll
        for (int j = 0; j < 4; ++j) {
          const float mn = fmaxf(m_prev[mi][j], tmv[mi][j]);
          const float fs = __builtin_amdgcn_exp2f(m_prev[mi][j] - mn);
          m_prev[mi][j] = mn;
          l_vec[mi][j] *= fs;
          #pragma unroll
          for (int hf = 0; hf < 4; ++hf) oacc[mi][hf][j] *= fs;
        }
    }
    #pragma unroll
    for (int mi = 0; mi < 2; ++mi)
      #pragma unroll
      for (int kf = 0; kf < 4; ++kf)
        #pragma unroll
        for (int j = 0; j < 4; ++j) {
          const float p = __builtin_amdgcn_exp2f(sf[mi][kf][j] - m_prev[mi][j]);
          Pl[(w * 32 + mi * 16 + g4 * 4 + j) * PSTR + kf * 16 + r16] = (short)f2bf(p);
        }

    // ---- PV + row-sums ----
    short8 vf[2][4];
    #pragma unroll
    for (int kk = 0; kk < 2; ++kk)
      #pragma unroll
      for (int hf = 0; hf < 4; ++hf)
        vf[kk][hf] = *(const short8*)&Vl[cur][(hf * 16 + r16) * LSTR + kk * 32 + g4 * 8];
    short8 pf[2][2];
    #pragma unroll
    for (int mi = 0; mi < 2; ++mi)
      #pragma unroll
      for (int kk = 0; kk < 2; ++kk)
        pf[mi][kk] = *(const short8*)&Pl[(w * 32 + mi * 16 + r16) * PSTR + kk * 32 + g4 * 8];
    #pragma unroll
    for (int mi = 0; mi < 2; ++mi) {
      #pragma unroll
      for (int kk = 0; kk < 2; ++kk) {
        l_vec[mi] = __builtin_amdgcn_mfma_f32_16x16x32_bf16(pf[mi][kk], ones, l_vec[mi], 0, 0, 0);
        #pragma unroll
        for (int hf = 0; hf < 4; ++hf)
          oacc[mi][hf] = __builtin_amdgcn_mfma_f32_16x16x32_bf16(pf[mi][kk], vf[kk][hf], oacc[mi][hf], 0, 0, 0);
      }
    }

    if (kt + 1 < NT) {
      #pragma unroll
      for (int i = 0; i < 2; ++i) {
        const int row = srow + i * 32;
        *(short8*)&Kl[cur ^ 1][row * LSTR + soff] = kreg[i];
        *(short8*)&Vl[cur ^ 1][row * LSTR + soff] = vreg[i];
      }
    }
  }

  #pragma unroll
  for (int mi = 0; mi < 2; ++mi)
    #pragma unroll
    for (int j = 0; j < 4; ++j) {
      const float rl = 1.f / l_vec[mi][j];
      const size_t orow = rowbase + qt * 128 + w * 32 + mi * 16 + g4 * 4 + j;
      #pragma unroll
      for (int hf = 0; hf < 4; ++hf)
        o[orow * DM + hh * 64 + hf * 16 + r16] = f2bf(oacc[mi][hf][j] * rl);
    }
}

// ---------------- launcher ----------------
extern "C" void kernel_launch(void* const* d_in, const int* in_sizes, int n_in,
                              void* d_out, int out_size, void* d_ws, size_t ws_size,
                              hipStream_t stream) {
  const float* x_in = (const float*)d_in[0];
  const float* Wq = (const float*)d_in[1];  const float* bq = (const float*)d_in[2];
  const float* Wk = (const float*)d_in[3];  const float* bk = (const float*)d_in[4];
  const float* Wv = (const float*)d_in[5];  const float* bv = (const float*)d_in[6];
  const float* Wo = (const float*)d_in[7];  const float* bo = (const float*)d_in[8];
  const float* W1 = (const float*)d_in[9];  const float* b1 = (const float*)d_in[10];
  const float* W2 = (const float*)d_in[11]; const float* b2 = (const float*)d_in[12];
  const float* ln1g = (const float*)d_in[13]; const float* ln1b = (const float*)d_in[14];
  const float* ln2g = (const float*)d_in[15]; const float* ln2b = (const float*)d_in[16];

  const size_t MB = 1u << 20;
  char* ws = (char*)d_ws;
  float*          x   = (float*)(ws + 0);                 // 16 MB fp32 residual
  unsigned short* h   = (unsigned short*)(ws + 16 * MB);  // 8 MB bf16 LN out
  unsigned short* qkv = (unsigned short*)(ws + 24 * MB);  // 24 MB bf16 [4096][3072]
  unsigned short* ob  = (unsigned short*)(ws + 48 * MB);  // 8 MB bf16 attn out
  unsigned short* f1  = (unsigned short*)(ws + 56 * MB);  // 32 MB bf16 ffn mid
  unsigned short* vt  = f1;                               // V^T reuses f1 (disjoint in time)
  unsigned short* wt  = (unsigned short*)(ws + 88 * MB);  // 8 MB bf16 transposed W (QKVO / W1)
  unsigned short* w2t = qkv;                              // W2^T parks in dead qkv buffer
  float*          b3  = (float*)(ws + 96 * MB);           // 48 KB qkv bias (all layers)

  concat3all<<<48, 256, 0, stream>>>(bq, bk, bv, b3);

  for (int i = 0; i < 4; ++i) {
    const size_t DD = (size_t)DM * DM;
    const float* xin  = (i == 0) ? x_in : x;              // layer-0 reads input directly
    float*       xout = (i == 3) ? (float*)d_out : x;     // layer-3 FFN2 writes output directly
    // --- attention sublayer ---
    tr_qkvo<<<dim3(32, 32, 4), 256, 0, stream>>>(
        Wq + i * DD, Wk + i * DD, Wv + i * DD, Wo + i * DD, wt);
    ln_kernel<<<MROWS, 256, 0, stream>>>(xin, ln1g + i * DM, ln1b + i * DM, h);
    gemm_bt<0, 0, 1><<<dim3(QKVLD / 128, MROWS / 128), 256, 0, stream>>>(
        h, wt, b3 + i * QKVLD, nullptr, nullptr, qkv, vt, MROWS, QKVLD, DM);
    attn_kernel<<<dim3(SLEN / 128, 32), 256, 0, stream>>>(qkv, vt, ob);
    gemm_n64<<<dim3(DM / 64, MROWS / 128), 256, 0, stream>>>(
        ob, wt + (size_t)3 * 1024 * 1024, bo + i * DM, xin, x, MROWS, DM, DM);
    // --- FFN sublayer ---
    tr_w12<<<8192, 256, 0, stream>>>(W1 + i * 4 * DD, W2 + i * 4 * DD, wt, w2t);
    ln_kernel<<<MROWS, 256, 0, stream>>>(x, ln2g + i * DM, ln2b + i * DM, h);
    gemm_bt<1, 0, 0><<<dim3(4 * DM / 128, MROWS / 128), 256, 0, stream>>>(
        h, wt, b1 + i * 4 * DM, nullptr, nullptr, f1, nullptr, MROWS, 4 * DM, DM);
    gemm_n64<<<dim3(DM / 64, MROWS / 128), 256, 0, stream>>>(
        f1, w2t, b2 + i * DM, x, xout, MROWS, DM, 4 * DM);
  }
}